// Round 1
// baseline (95.266 us; speedup 1.0000x reference)
//
#include <hip/hip_runtime.h>
#include <math.h>

// ---------------- constants ----------------
#define NLUT     4096
#define LUT_LO   (-0.33)
#define LUT_H    (0.0004)
#define LUT_INVH (2500.0f)   // 1/LUT_H
#define LUT_BIAS (825.0f)    // -LUT_LO/LUT_H
#define BAND_LO  (-0.35f)
#define BAND_HI  (1.28f)

// ---------------- ws layout (bytes) ----------------
#define WS_LUT    0          // float2[4096]  (32768)
#define WS_TH2T   32768      // float[36864]  (147456) -> 180224
#define WS_RAW1   180224     // float[262144] (1048576) -> 1228800
#define WS_MASK   1228800    // u64[4096]     (32768)  -> 1261568
#define WS_STAT1  1261568    // float[128]    (512)    -> 1262080  (mean1|rstd1)
#define WS_SUMS2  1262080    // float[128]    (512)    -> 1262592  (sum|sumsq)
#define WS_THMAX  1262592    // u32
#define WS_THMIN  1262596    // u32
#define WS_TOTAL  1262600

__device__ __forceinline__ double f_exact(double d) {
    const double nvt = 1.5 * 0.026;
    double a1 = d / nvt;         a1 = fmin(fmax(a1, -30.0), 30.0);
    double a2 = (d - 0.1) / nvt; a2 = fmin(fmax(a2, -30.0), 30.0);
    double s1 = log1p(exp(a1));
    double s2 = log1p(exp(a2));
    return 0.0005625 * (s1 * s1 - s2 * s2);
}

// K0: blocks 0..15 build LUT (f64 math); blocks 16..159 transpose theta2 + min/max
__global__ __launch_bounds__(256) void k0_prep(const float* __restrict__ theta2,
        float* __restrict__ lutg, float* __restrict__ th2t, unsigned* __restrict__ mm)
{
    int blk = blockIdx.x;
    if (blk < 16) {
        int i = blk * 256 + threadIdx.x;             // 0..4095
        double f0 = f_exact(LUT_LO + (double)i * LUT_H);
        double f1 = f_exact(LUT_LO + (double)(i + 1) * LUT_H);
        lutg[2 * i]     = (float)f0;
        lutg[2 * i + 1] = (float)(f1 - f0);
    } else {
        int i = (blk - 16) * 256 + threadIdx.x;      // 0..36863
        int p = i & 63, k = i >> 6;
        float v = theta2[p * 576 + k];
        th2t[k * 64 + p] = v;
        __shared__ float smin[256], smax[256];
        smin[threadIdx.x] = v; smax[threadIdx.x] = v;
        __syncthreads();
        for (int s = 128; s > 0; s >>= 1) {
            if (threadIdx.x < s) {
                smin[threadIdx.x] = fminf(smin[threadIdx.x], smin[threadIdx.x + s]);
                smax[threadIdx.x] = fmaxf(smax[threadIdx.x], smax[threadIdx.x + s]);
            }
            __syncthreads();
        }
        if (threadIdx.x == 0) {
            atomicMax(&mm[0], __float_as_uint(smax[0]));   // thetas > 0 -> uint order ok
            atomicMin(&mm[1], __float_as_uint(smin[0]));
        }
    }
}

// K1: dense conv1 via LDS LUT (lerp). 512 blocks = b(4) x rowpair(16) x pgroup(8).
// Wave w handles planes pg*8 + 2w .. +1; lane = (row within pair, x).
__global__ __launch_bounds__(256) void k1_conv1(const float* __restrict__ x,
    const float* __restrict__ theta1, const float* __restrict__ psc,
    const float* __restrict__ psh, const float* __restrict__ ls1,
    const float* __restrict__ lutg, float* __restrict__ raw1)
{
    __shared__ float2 lut[NLUT];
    {
        const float4* src = (const float4*)lutg;
        float4* dst = (float4*)lut;
        #pragma unroll
        for (int i = threadIdx.x; i < NLUT / 2; i += 256) dst[i] = src[i];
    }
    __syncthreads();

    int blk = blockIdx.x;
    int pg = blk & 7;
    int yp = (blk >> 3) & 15;
    int b  = blk >> 7;
    int wv = __builtin_amdgcn_readfirstlane((int)threadIdx.x >> 6);
    int lane = threadIdx.x & 63;
    int r = lane >> 5, xc = lane & 31;
    int y = yp * 2 + r;
    int p0 = pg * 8 + wv * 2;

    float scale = psc[0], shift = psh[0];
    const float* xb  = x + b * 65536;
    const float* t0p = theta1 + p0 * 576;
    const float* t1p = t0p + 576;
    float acc0 = 0.f, acc1 = 0.f;

    #pragma unroll
    for (int j = 0; j < 9; ++j) {
        int ny = y + j / 3 - 1, nx = xc + j % 3 - 1;
        if ((unsigned)ny < 32u && (unsigned)nx < 32u) {  // padding taps are exactly 0
            const float* px = xb + ny * 32 + nx;
            #pragma unroll 4
            for (int c = 0; c < 64; ++c) {
                float v  = fmaf(px[c * 1024], scale, shift);
                float t0 = t0p[c * 9 + j];               // wave-uniform -> s_load
                float t1 = t1p[c * 9 + j];
                float q0 = fmaf(v - t0, LUT_INVH, LUT_BIAS);
                q0 = fminf(fmaxf(q0, 0.f), 4095.0f);
                int   i0 = (int)q0;
                float fr0 = q0 - (float)i0;
                float2 e0 = lut[i0];
                acc0 = fmaf(fr0, e0.y, acc0 + e0.x);
                float q1 = fmaf(v - t1, LUT_INVH, LUT_BIAS);
                q1 = fminf(fmaxf(q1, 0.f), 4095.0f);
                int   i1 = (int)q1;
                float fr1 = q1 - (float)i1;
                float2 e1 = lut[i1];
                acc1 = fmaf(fr1, e1.y, acc1 + e1.x);
            }
        }
    }
    float l1 = ls1[0];
    int o = ((b * 64 + p0) * 32 + y) * 32 + xc;
    raw1[o]        = l1 * acc0;
    raw1[o + 1024] = l1 * acc1;
}

// K2: BN1 stats, one block per channel (deterministic tree reduce)
__global__ __launch_bounds__(256) void k2_stats1(const float* __restrict__ raw1,
                                                 float* __restrict__ stat1)
{
    int p = blockIdx.x;
    float s = 0.f, q = 0.f;
    for (int b = 0; b < 4; ++b) {
        const float* base = raw1 + (b * 64 + p) * 1024;
        for (int k = threadIdx.x; k < 1024; k += 256) {
            float v = base[k];
            s += v; q += v * v;
        }
    }
    __shared__ float ss[256], sq[256];
    ss[threadIdx.x] = s; sq[threadIdx.x] = q;
    __syncthreads();
    for (int st = 128; st > 0; st >>= 1) {
        if (threadIdx.x < st) {
            ss[threadIdx.x] += ss[threadIdx.x + st];
            sq[threadIdx.x] += sq[threadIdx.x + st];
        }
        __syncthreads();
    }
    if (threadIdx.x == 0) {
        double mean = (double)ss[0] / 4096.0;
        double var  = (double)sq[0] / 4096.0 - mean * mean;
        if (var < 0) var = 0;
        stat1[p]      = (float)mean;
        stat1[64 + p] = (float)(1.0 / sqrt(var + 1e-5));
    }
}

// K3: BN1 apply in place + per-pixel channel activity masks for sparse conv2
__global__ __launch_bounds__(256) void k3_bn1mask(float* __restrict__ v2,
    const float* __restrict__ stat1, const float* __restrict__ g1,
    const float* __restrict__ b1, const unsigned* __restrict__ mm,
    unsigned long long* __restrict__ masks)
{
    int idx = blockIdx.x * 256 + threadIdx.x;    // < 262144
    int c = (idx >> 10) & 63;
    float v = v2[idx];
    v = (v - stat1[c]) * stat1[64 + c];
    v = v * g1[c] + b1[c];
    v2[idx] = v;
    float tmax = __uint_as_float(mm[0]);
    float tmin = __uint_as_float(mm[1]);
    if (v > tmin + BAND_LO && v < tmax + BAND_HI) {
        int b = idx >> 16;
        int pix = idx & 1023;
        atomicOr(&masks[b * 1024 + pix], 1ull << c);
    }
}

// K4: sparse conv2. Wave per pixel-group, lane = output plane p. Exact f32 eval.
__global__ __launch_bounds__(256) void k4_conv2(const float* __restrict__ v2,
    const float* __restrict__ th2t, const unsigned long long* __restrict__ masks,
    const float* __restrict__ ls2, float* __restrict__ out, float* __restrict__ sums2)
{
    int wv = __builtin_amdgcn_readfirstlane((int)threadIdx.x >> 6);
    int lane = threadIdx.x & 63;
    int W = blockIdx.x * 4 + wv;                 // 1024 waves
    float l2 = ls2[0];
    const float inv_nvt = (float)(1.0 / (1.5 * 0.026));
    float lsum = 0.f, lsq = 0.f;

    for (int i = 0; i < 4; ++i) {
        int P = W * 4 + i;                       // 0..4095
        int b = P >> 10, rem = P & 1023;
        int y = rem >> 5, xq = rem & 31;
        float acc = 0.f;
        #pragma unroll
        for (int j = 0; j < 9; ++j) {
            int ny = y + j / 3 - 1, nx = xq + j % 3 - 1;
            if ((unsigned)ny < 32u && (unsigned)nx < 32u) {
                unsigned long long m = masks[b * 1024 + ny * 32 + nx];
                while (m) {
                    int c = __ffsll((long long)m) - 1;
                    m &= m - 1;
                    float v  = v2[((b * 64 + c) * 32 + ny) * 32 + nx]; // uniform
                    float th = th2t[(c * 9 + j) * 64 + lane];          // coalesced
                    float d = v - th;
                    if (d > BAND_LO && d < BAND_HI) {
                        float a1 = fminf(fmaxf(d * inv_nvt, -30.f), 30.f);
                        float a2 = fminf(fmaxf((d - 0.1f) * inv_nvt, -30.f), 30.f);
                        float s1 = __logf(1.f + __expf(a1));
                        float s2 = __logf(1.f + __expf(a2));
                        acc += (s1 * s1 - s2 * s2);
                    }
                }
            }
        }
        float r2 = 0.0005625f * l2 * acc;
        out[((b * 64 + lane) * 32 + y) * 32 + xq] = r2;
        lsum += r2; lsq += r2 * r2;
    }
    __shared__ float ss[256], sq[256];
    ss[threadIdx.x] = lsum; sq[threadIdx.x] = lsq;
    __syncthreads();
    if (threadIdx.x < 64) {
        float a  = ss[threadIdx.x] + ss[threadIdx.x + 64] + ss[threadIdx.x + 128] + ss[threadIdx.x + 192];
        float qq = sq[threadIdx.x] + sq[threadIdx.x + 64] + sq[threadIdx.x + 128] + sq[threadIdx.x + 192];
        atomicAdd(&sums2[threadIdx.x], a);
        atomicAdd(&sums2[64 + threadIdx.x], qq);
    }
}

// K6: BN2 apply (stats finalized inline) + residual add, in place on d_out
__global__ __launch_bounds__(256) void k6_final(float* __restrict__ out,
    const float* __restrict__ x, const float* __restrict__ sums2,
    const float* __restrict__ g2, const float* __restrict__ b2)
{
    int idx = blockIdx.x * 256 + threadIdx.x;    // < 262144
    int p = (idx >> 10) & 63;
    float m   = sums2[p] * (1.f / 4096.f);
    float var = sums2[64 + p] * (1.f / 4096.f) - m * m;
    var = fmaxf(var, 0.f);
    float rstd = rsqrtf(var + 1e-5f);
    out[idx] = (out[idx] - m) * rstd * g2[p] + b2[p] + x[idx];
}

extern "C" void kernel_launch(void* const* d_in, const int* in_sizes, int n_in,
                              void* d_out, int out_size, void* d_ws, size_t ws_size,
                              hipStream_t stream)
{
    const float* x   = (const float*)d_in[0];
    const float* th1 = (const float*)d_in[1];
    const float* th2 = (const float*)d_in[2];
    const float* psc = (const float*)d_in[3];
    const float* psh = (const float*)d_in[4];
    const float* l1  = (const float*)d_in[5];
    const float* l2  = (const float*)d_in[6];
    const float* g1  = (const float*)d_in[7];
    const float* b1  = (const float*)d_in[8];
    const float* g2  = (const float*)d_in[9];
    const float* b2  = (const float*)d_in[10];
    float* out = (float*)d_out;
    char* ws = (char*)d_ws;
    if (ws_size < (size_t)WS_TOTAL) return;  // defensive: leave output poisoned -> loud fail

    float* lut   = (float*)(ws + WS_LUT);
    float* th2t  = (float*)(ws + WS_TH2T);
    float* raw1  = (float*)(ws + WS_RAW1);
    unsigned long long* masks = (unsigned long long*)(ws + WS_MASK);
    float* stat1 = (float*)(ws + WS_STAT1);
    float* sums2 = (float*)(ws + WS_SUMS2);
    unsigned* mm = (unsigned*)(ws + WS_THMAX);

    // zero masks + stat1 + sums2 + thmax in one shot; thmin init to big uint
    hipMemsetAsync(ws + WS_MASK, 0, WS_THMIN - WS_MASK, stream);
    hipMemsetAsync(ws + WS_THMIN, 0x7F, 4, stream);

    k0_prep  <<<160,  256, 0, stream>>>(th2, lut, th2t, mm);
    k1_conv1 <<<512,  256, 0, stream>>>(x, th1, psc, psh, l1, lut, raw1);
    k2_stats1<<<64,   256, 0, stream>>>(raw1, stat1);
    k3_bn1mask<<<1024,256, 0, stream>>>(raw1, stat1, g1, b1, mm, masks);
    k4_conv2 <<<256,  256, 0, stream>>>(raw1, th2t, masks, l2, out, sums2);
    k6_final <<<1024, 256, 0, stream>>>(out, x, sums2, g2, b2);
}